// Round 8
// baseline (201.466 us; speedup 1.0000x reference)
//
#include <hip/hip_runtime.h>

#define N_NODES 50000
#define NB 782          // buckets of 64 dst nodes: ceil(50000/64)
#define PA_CH 4096      // edges per block in bucket_scatter
#define CAP 2048        // max edges per bucket (avg 1023; uniform-random tail safe)

typedef __attribute__((ext_vector_type(8))) short bf16x8;
typedef __attribute__((ext_vector_type(4))) float f32x4;

// bf16 helpers (RNE pack, shift unpack)
static __device__ __forceinline__ unsigned short f2bf(float f) {
    unsigned int u = __float_as_uint(f);
    u += 0x7fffu + ((u >> 16) & 1u);
    return (unsigned short)(u >> 16);
}
static __device__ __forceinline__ float bfl(unsigned int u) { return __uint_as_float(u << 16); }
static __device__ __forceinline__ float bfh(unsigned int u) { return __uint_as_float(u & 0xffff0000u); }

// ================= CSR build: 2-level bucket sort (deterministic) =================

__global__ void zero_gcnt(int* __restrict__ g) {
    int i = blockIdx.x * 256 + threadIdx.x;
    if (i < NB) g[i] = 0;
}

__global__ __launch_bounds__(256) void bucket_hist(const int* __restrict__ dst,
                                                   int* __restrict__ gcnt, int E) {
    __shared__ int bins[NB];
    for (int i = threadIdx.x; i < NB; i += 256) bins[i] = 0;
    __syncthreads();
    for (int i = blockIdx.x * 256 + threadIdx.x; i < E; i += gridDim.x * 256)
        atomicAdd(&bins[dst[i] >> 6], 1);
    __syncthreads();
    for (int i = threadIdx.x; i < NB; i += 256) {
        int c = bins[i];
        if (c) atomicAdd(&gcnt[i], c);
    }
}

__global__ __launch_bounds__(1024) void scan_nb(const int* __restrict__ gcnt,
                                                int* __restrict__ bptr, int* __restrict__ gcur,
                                                int* __restrict__ row_ptr, int E) {
    int tid = threadIdx.x;
    int v = (tid < NB) ? gcnt[tid] : 0;
    int lane = tid & 63, wv = tid >> 6;
    int incl = v;
    for (int off = 1; off < 64; off <<= 1) {
        int t = __shfl_up(incl, off);
        if (lane >= off) incl += t;
    }
    __shared__ int ws[16];
    if (lane == 63) ws[wv] = incl;
    __syncthreads();
    int woff = 0;
    for (int i = 0; i < wv; ++i) woff += ws[i];
    int excl = woff + incl - v;
    if (tid < NB) { bptr[tid] = excl; gcur[tid] = excl; }
    if (tid == NB - 1) { bptr[NB] = excl + v; row_ptr[N_NODES] = E; }
}

// pass A: scatter packed (src | dst_low6<<16) into bucket regions (order nondeterministic,
// harmless: pass B fully sorts each bucket)
__global__ __launch_bounds__(256) void bucket_scatter(const int* __restrict__ src,
                                                      const int* __restrict__ dst,
                                                      int* __restrict__ gcur,
                                                      unsigned* __restrict__ ebuf, int E) {
    __shared__ int cnt[NB];
    __shared__ int run[NB];
    int base = blockIdx.x * PA_CH;
    int end = base + PA_CH; if (end > E) end = E;
    for (int i = threadIdx.x; i < NB; i += 256) cnt[i] = 0;
    __syncthreads();
    for (int i = base + threadIdx.x; i < end; i += 256)
        atomicAdd(&cnt[dst[i] >> 6], 1);
    __syncthreads();
    for (int i = threadIdx.x; i < NB; i += 256) {
        int c = cnt[i];
        run[i] = c ? atomicAdd(&gcur[i], c) : 0;
    }
    __syncthreads();
    for (int i = base + threadIdx.x; i < end; i += 256) {
        int d = dst[i];
        int b = d >> 6;
        int pos = atomicAdd(&run[b], 1);
        ebuf[pos] = (unsigned)src[i] | ((unsigned)(d & 63) << 16);
    }
}

// pass B: per-bucket in-LDS BITONIC sort by full (dst_low6<<16 | src) key.
// Output is a deterministic function of the edge multiset (duplicate keys are
// identical u16 values), so edge_src is bit-identical across replays.
__global__ __launch_bounds__(256) void bucket_sort(const unsigned* __restrict__ ebuf,
                                                   const int* __restrict__ bptr,
                                                   unsigned short* __restrict__ edge_src,
                                                   int* __restrict__ row_ptr) {
    int b = blockIdx.x;
    int start = bptr[b], bend = bptr[b + 1];
    int n = bend - start; if (n > CAP) n = CAP;
    int m = 2; while (m < n) m <<= 1;   // power-of-2 sort size
    __shared__ unsigned key[CAP];
    __shared__ int bins[64], pref[64];
    int tid = threadIdx.x;
    for (int i = tid; i < m; i += 256) key[i] = (i < n) ? ebuf[start + i] : 0xFFFFFFFFu;
    if (tid < 64) bins[tid] = 0;
    __syncthreads();
    for (int i = tid; i < n; i += 256) atomicAdd(&bins[key[i] >> 16], 1);
    for (int k = 2; k <= m; k <<= 1) {
        for (int j = k >> 1; j > 0; j >>= 1) {
            __syncthreads();
            for (int i = tid; i < m; i += 256) {
                int ixj = i ^ j;
                if (ixj > i) {
                    unsigned a = key[i], c = key[ixj];
                    bool asc = ((i & k) == 0);
                    if ((a > c) == asc) { key[i] = c; key[ixj] = a; }
                }
            }
        }
    }
    __syncthreads();
    if (tid < 64) {
        int v = bins[tid];
        int incl = v;
        for (int off = 1; off < 64; off <<= 1) {
            int t = __shfl_up(incl, off);
            if (tid >= off) incl += t;
        }
        pref[tid] = incl - v;
    }
    __syncthreads();
    for (int i = tid; i < n; i += 256)
        edge_src[start + i] = (unsigned short)(key[i] & 0xffffu);
    int d0 = b * 64;
    if (tid < 64 && d0 + tid < N_NODES) row_ptr[d0 + tid] = start + pref[tid];
}

// ================= weight prep =================

// pre-pack all three W into bf16 fragments Wb[ct][kt][lane][8] (contiguous wb0|wb1|wb2)
__global__ void prep_all(const float* __restrict__ W0, const float* __restrict__ W1,
                         const float* __restrict__ W2, short* __restrict__ Wb) {
    int i = blockIdx.x * 256 + threadIdx.x;
    if (i >= 19 * 2048) return;
    const float* W; int fout; int local;
    if (i < 8 * 2048)       { W = W0; fout = 128; local = i; }
    else if (i < 16 * 2048) { W = W1; fout = 128; local = i - 8 * 2048; }
    else                    { W = W2; fout = 40;  local = i - 16 * 2048; }
    int j = local & 7;
    int l = (local >> 3) & 63;
    int kt = (local >> 9) & 3;
    int ct = local >> 11;
    int col = ct * 16 + (l & 15);
    int k = kt * 32 + (l >> 4) * 8 + j;
    float v = (col < fout) ? W[col * 128 + k] : 0.0f;
    Wb[i] = (short)f2bf(v);
}

// ================= standalone MFMA GEMM (layer 0: x f32 -> h0 bf16) =================

template <int FT>
__global__ __launch_bounds__(256) void gemm_mfma(const float* __restrict__ inp,
                                                 const short* __restrict__ Wb,
                                                 unsigned short* __restrict__ out, int fout) {
    const int l = threadIdx.x & 63;
    const int w = threadIdx.x >> 6;
    const int r16 = l & 15;
    const int khalf = l >> 4;
    int rowA = blockIdx.x * 64 + w * 16 + r16;
    if (rowA >= N_NODES) rowA = N_NODES - 1;  // garbage stays in unstored rows

    f32x4 acc[FT];
#pragma unroll
    for (int ct = 0; ct < FT; ++ct) acc[ct] = (f32x4){0.f, 0.f, 0.f, 0.f};

#pragma unroll
    for (int kt = 0; kt < 4; ++kt) {
        const float* ip = inp + (size_t)rowA * 128 + kt * 32 + khalf * 8;
        float4 f0 = ((const float4*)ip)[0];
        float4 f1 = ((const float4*)ip)[1];
        bf16x8 a;
        a[0] = (short)f2bf(f0.x); a[1] = (short)f2bf(f0.y);
        a[2] = (short)f2bf(f0.z); a[3] = (short)f2bf(f0.w);
        a[4] = (short)f2bf(f1.x); a[5] = (short)f2bf(f1.y);
        a[6] = (short)f2bf(f1.z); a[7] = (short)f2bf(f1.w);
#pragma unroll
        for (int ct = 0; ct < FT; ++ct) {
            bf16x8 bfr = *(const bf16x8*)(Wb + (((ct * 4 + kt) * 64 + l) * 8));
            acc[ct] = __builtin_amdgcn_mfma_f32_16x16x32_bf16(a, bfr, acc[ct], 0, 0, 0);
        }
    }

    const int rowD0 = blockIdx.x * 64 + w * 16 + khalf * 4;
#pragma unroll
    for (int ct = 0; ct < FT; ++ct) {
        int col = ct * 16 + r16;
#pragma unroll
        for (int rr = 0; rr < 4; ++rr) {
            int row = rowD0 + rr;
            if (row < N_NODES && col < fout)
                out[(size_t)row * fout + col] = f2bf(acc[ct][rr]);
        }
    }
}

// ================= fused gather + GEMM (layers 1,2) =================
// Block = 256 threads = 16 nodes. Phase 1: gather bf16 h rows + bias, ReLU,
// into LDS agg[16][132] f32 (pad 132 keeps ds_read_b128 conflicts <=2-way).
// Phase 2: MFMA 16x128 tile; wave w owns col-tiles ct = w, w+4, ...
template <int NCT>
__global__ __launch_bounds__(256) void gather_gemm(const unsigned short* __restrict__ h,
                                                   const int* __restrict__ row_ptr,
                                                   const unsigned short* __restrict__ es,
                                                   const float* __restrict__ bias,
                                                   const short* __restrict__ Wb,
                                                   unsigned short* __restrict__ out, int fout) {
    __shared__ float agg[16][132];
    const int node0 = blockIdx.x * 16;

    {   // ---- gather phase: 16 threads per node, 8 feats each ----
        const int nl = threadIdx.x >> 4;
        const int q  = threadIdx.x & 15;
        const int node = node0 + nl;
        int beg = row_ptr[node], end = row_ptr[node + 1];
        float acc[8];
        float4 c0 = ((const float4*)bias)[q * 2];
        float4 c1 = ((const float4*)bias)[q * 2 + 1];
        acc[0] = c0.x; acc[1] = c0.y; acc[2] = c0.z; acc[3] = c0.w;
        acc[4] = c1.x; acc[5] = c1.y; acc[6] = c1.z; acc[7] = c1.w;
        int e = beg;
        for (; e + 1 < end; e += 2) {
            int s0 = es[e], s1 = es[e + 1];
            const uint4 v0 = ((const uint4*)(h + (size_t)s0 * 128))[q];
            const uint4 v1 = ((const uint4*)(h + (size_t)s1 * 128))[q];
            acc[0] += bfl(v0.x); acc[1] += bfh(v0.x);
            acc[2] += bfl(v0.y); acc[3] += bfh(v0.y);
            acc[4] += bfl(v0.z); acc[5] += bfh(v0.z);
            acc[6] += bfl(v0.w); acc[7] += bfh(v0.w);
            acc[0] += bfl(v1.x); acc[1] += bfh(v1.x);
            acc[2] += bfl(v1.y); acc[3] += bfh(v1.y);
            acc[4] += bfl(v1.z); acc[5] += bfh(v1.z);
            acc[6] += bfl(v1.w); acc[7] += bfh(v1.w);
        }
        if (e < end) {
            int s = es[e];
            const uint4 v = ((const uint4*)(h + (size_t)s * 128))[q];
            acc[0] += bfl(v.x); acc[1] += bfh(v.x);
            acc[2] += bfl(v.y); acc[3] += bfh(v.y);
            acc[4] += bfl(v.z); acc[5] += bfh(v.z);
            acc[6] += bfl(v.w); acc[7] += bfh(v.w);
        }
        float* row = &agg[nl][q * 8];
        ((float4*)row)[0] = make_float4(fmaxf(acc[0], 0.f), fmaxf(acc[1], 0.f),
                                        fmaxf(acc[2], 0.f), fmaxf(acc[3], 0.f));
        ((float4*)row)[1] = make_float4(fmaxf(acc[4], 0.f), fmaxf(acc[5], 0.f),
                                        fmaxf(acc[6], 0.f), fmaxf(acc[7], 0.f));
    }
    __syncthreads();

    // ---- MFMA phase ----
    const int l = threadIdx.x & 63;
    const int w = threadIdx.x >> 6;
    const int r16 = l & 15;
    const int khalf = l >> 4;
    f32x4 acc[(NCT + 3) / 4];
#pragma unroll
    for (int i = 0; i < (NCT + 3) / 4; ++i) acc[i] = (f32x4){0.f, 0.f, 0.f, 0.f};

#pragma unroll
    for (int kt = 0; kt < 4; ++kt) {
        const float* ap = &agg[r16][kt * 32 + khalf * 8];
        float4 f0 = ((const float4*)ap)[0];
        float4 f1 = ((const float4*)ap)[1];
        bf16x8 a;
        a[0] = (short)f2bf(f0.x); a[1] = (short)f2bf(f0.y);
        a[2] = (short)f2bf(f0.z); a[3] = (short)f2bf(f0.w);
        a[4] = (short)f2bf(f1.x); a[5] = (short)f2bf(f1.y);
        a[6] = (short)f2bf(f1.z); a[7] = (short)f2bf(f1.w);
        int i = 0;
#pragma unroll
        for (int ct = w; ct < NCT; ct += 4, ++i) {
            bf16x8 bfr = *(const bf16x8*)(Wb + (((ct * 4 + kt) * 64 + l) * 8));
            acc[i] = __builtin_amdgcn_mfma_f32_16x16x32_bf16(a, bfr, acc[i], 0, 0, 0);
        }
    }

    {
        int i = 0;
#pragma unroll
        for (int ct = w; ct < NCT; ct += 4, ++i) {
            int col = ct * 16 + r16;
            if (col < fout) {
#pragma unroll
                for (int rr = 0; rr < 4; ++rr)
                    out[(size_t)(node0 + khalf * 4 + rr) * fout + col] = f2bf(acc[i][rr]);
            }
        }
    }
}

// ================= final gather (F=40, bf16 in -> f32 out + bias) =================

__global__ void gather_f40_bf(const unsigned short* __restrict__ h,
                              const int* __restrict__ row_ptr,
                              const unsigned short* __restrict__ es,
                              const float* __restrict__ b,
                              float* __restrict__ out) {
    int gid = blockIdx.x * blockDim.x + threadIdx.x;
    int node = gid / 5;
    int q = gid - node * 5;
    if (node >= N_NODES) return;
    int beg = row_ptr[node];
    int end = row_ptr[node + 1];
    float acc[8];
#pragma unroll
    for (int j = 0; j < 8; ++j) acc[j] = b[q * 8 + j];
    int e = beg;
    for (; e + 1 < end; e += 2) {
        int s0 = es[e], s1 = es[e + 1];
        const uint4 v0 = *(const uint4*)(h + (size_t)s0 * 40 + q * 8);
        const uint4 v1 = *(const uint4*)(h + (size_t)s1 * 40 + q * 8);
        acc[0] += bfl(v0.x); acc[1] += bfh(v0.x);
        acc[2] += bfl(v0.y); acc[3] += bfh(v0.y);
        acc[4] += bfl(v0.z); acc[5] += bfh(v0.z);
        acc[6] += bfl(v0.w); acc[7] += bfh(v0.w);
        acc[0] += bfl(v1.x); acc[1] += bfh(v1.x);
        acc[2] += bfl(v1.y); acc[3] += bfh(v1.y);
        acc[4] += bfl(v1.z); acc[5] += bfh(v1.z);
        acc[6] += bfl(v1.w); acc[7] += bfh(v1.w);
    }
    if (e < end) {
        int s = es[e];
        const uint4 v = *(const uint4*)(h + (size_t)s * 40 + q * 8);
        acc[0] += bfl(v.x); acc[1] += bfh(v.x);
        acc[2] += bfl(v.y); acc[3] += bfh(v.y);
        acc[4] += bfl(v.z); acc[5] += bfh(v.z);
        acc[6] += bfl(v.w); acc[7] += bfh(v.w);
    }
    float* o = out + (size_t)node * 40 + q * 8;
    ((float4*)o)[0] = make_float4(acc[0], acc[1], acc[2], acc[3]);
    ((float4*)o)[1] = make_float4(acc[4], acc[5], acc[6], acc[7]);
}

// ================= host =================

extern "C" void kernel_launch(void* const* d_in, const int* in_sizes, int n_in,
                              void* d_out, int out_size, void* d_ws, size_t ws_size,
                              hipStream_t stream) {
    const float* x  = (const float*)d_in[0];
    const int*   ei = (const int*)d_in[1];
    const float* W0 = (const float*)d_in[2];
    const float* b0 = (const float*)d_in[3];
    const float* W1 = (const float*)d_in[4];
    const float* b1 = (const float*)d_in[5];
    const float* W2 = (const float*)d_in[6];
    const float* b2 = (const float*)d_in[7];
    float* out = (float*)d_out;

    const int E = in_sizes[1] / 2;
    const int* src = ei;
    const int* dst = ei + E;

    // workspace layout
    char* p = (char*)d_ws;
    unsigned short* hb0 = (unsigned short*)p;  p += (size_t)N_NODES * 128 * 2;  // L0 out (bf16)
    unsigned short* hb1 = (unsigned short*)p;  p += (size_t)N_NODES * 128 * 2;  // F1 out (bf16)
    unsigned short* hb2 = (unsigned short*)p;  p += (size_t)N_NODES * 40 * 2;   // F2 out (bf16)
    short* wb = (short*)p;                     p += 19 * 2048 * 2;              // wb0|wb1|wb2
    unsigned* ebuf = (unsigned*)p;             p += (size_t)E * 4;
    int* row_ptr = (int*)p;                    p += (N_NODES + 1) * 4;
    int* bptr = (int*)p;                       p += (NB + 1) * 4;
    int* gcnt = (int*)p;                       p += NB * 4;
    int* gcur = (int*)p;                       p += NB * 4;
    unsigned short* edge_src = (unsigned short*)p;  // E u16

    short* wb0 = wb;
    short* wb1 = wb + 8 * 2048;
    short* wb2 = wb + 16 * 2048;

    // ---- CSR build (deterministic: full (dst,src) sort within buckets) ----
    zero_gcnt<<<4, 256, 0, stream>>>(gcnt);
    bucket_hist<<<256, 256, 0, stream>>>(dst, gcnt, E);
    scan_nb<<<1, 1024, 0, stream>>>(gcnt, bptr, gcur, row_ptr, E);
    bucket_scatter<<<(E + PA_CH - 1) / PA_CH, 256, 0, stream>>>(src, dst, gcur, ebuf, E);
    bucket_sort<<<NB, 256, 0, stream>>>(ebuf, bptr, edge_src, row_ptr);

    // ---- weight prep ----
    prep_all<<<(19 * 2048 + 255) / 256, 256, 0, stream>>>(W0, W1, W2, wb);

    // ---- layer 0: h0 = bf16(x @ W0^T) ----
    gemm_mfma<8><<<(N_NODES + 63) / 64, 256, 0, stream>>>(x, wb0, hb0, 128);

    // ---- layer 1 fused: h1 = bf16(relu(gather(h0)+b0) @ W1^T) ----
    gather_gemm<8><<<N_NODES / 16, 256, 0, stream>>>(hb0, row_ptr, edge_src, b0, wb1, hb1, 128);

    // ---- layer 2 fused: h2 = bf16(relu(gather(h1)+b1) @ W2^T) ----
    gather_gemm<3><<<N_NODES / 16, 256, 0, stream>>>(hb1, row_ptr, edge_src, b1, wb2, hb2, 40);

    // ---- final aggregation: out = gather(h2) + b2 ----
    gather_f40_bf<<<(N_NODES * 5 + 255) / 256, 256, 0, stream>>>(hb2, row_ptr, edge_src, b2, out);
}

// Round 9
// 177.191 us; speedup vs baseline: 1.1370x; 1.1370x over previous
//
#include <hip/hip_runtime.h>

#define N_NODES 50000
#define NB 782          // buckets of 64 dst nodes: ceil(50000/64)
#define PA_CH 4096      // edges per block in bucket_scatter
#define CAP 2048        // max edges per bucket (avg 1023; uniform-random tail safe)

typedef __attribute__((ext_vector_type(8))) short bf16x8;
typedef __attribute__((ext_vector_type(4))) float f32x4;

// bf16 helpers (RNE pack, shift unpack)
static __device__ __forceinline__ unsigned short f2bf(float f) {
    unsigned int u = __float_as_uint(f);
    u += 0x7fffu + ((u >> 16) & 1u);
    return (unsigned short)(u >> 16);
}
static __device__ __forceinline__ float bfl(unsigned int u) { return __uint_as_float(u << 16); }
static __device__ __forceinline__ float bfh(unsigned int u) { return __uint_as_float(u & 0xffff0000u); }

// ================= CSR build: 2-level bucket sort (deterministic) =================

__global__ void zero_gcnt(int* __restrict__ g) {
    int i = blockIdx.x * 256 + threadIdx.x;
    if (i < NB) g[i] = 0;
}

__global__ __launch_bounds__(256) void bucket_hist(const int* __restrict__ dst,
                                                   int* __restrict__ gcnt, int E) {
    __shared__ int bins[NB];
    for (int i = threadIdx.x; i < NB; i += 256) bins[i] = 0;
    __syncthreads();
    for (int i = blockIdx.x * 256 + threadIdx.x; i < E; i += gridDim.x * 256)
        atomicAdd(&bins[dst[i] >> 6], 1);
    __syncthreads();
    for (int i = threadIdx.x; i < NB; i += 256) {
        int c = bins[i];
        if (c) atomicAdd(&gcnt[i], c);
    }
}

__global__ __launch_bounds__(1024) void scan_nb(const int* __restrict__ gcnt,
                                                int* __restrict__ bptr, int* __restrict__ gcur,
                                                int* __restrict__ row_ptr, int E) {
    int tid = threadIdx.x;
    int v = (tid < NB) ? gcnt[tid] : 0;
    int lane = tid & 63, wv = tid >> 6;
    int incl = v;
    for (int off = 1; off < 64; off <<= 1) {
        int t = __shfl_up(incl, off);
        if (lane >= off) incl += t;
    }
    __shared__ int ws[16];
    if (lane == 63) ws[wv] = incl;
    __syncthreads();
    int woff = 0;
    for (int i = 0; i < wv; ++i) woff += ws[i];
    int excl = woff + incl - v;
    if (tid < NB) { bptr[tid] = excl; gcur[tid] = excl; }
    if (tid == NB - 1) { bptr[NB] = excl + v; row_ptr[N_NODES] = E; }
}

// pass A: scatter packed (src | dst_low6<<16) into bucket regions (order nondeterministic,
// harmless: pass B canonicalizes each bucket)
__global__ __launch_bounds__(256) void bucket_scatter(const int* __restrict__ src,
                                                      const int* __restrict__ dst,
                                                      int* __restrict__ gcur,
                                                      unsigned* __restrict__ ebuf, int E) {
    __shared__ int cnt[NB];
    __shared__ int run[NB];
    int base = blockIdx.x * PA_CH;
    int end = base + PA_CH; if (end > E) end = E;
    for (int i = threadIdx.x; i < NB; i += 256) cnt[i] = 0;
    __syncthreads();
    for (int i = base + threadIdx.x; i < end; i += 256)
        atomicAdd(&cnt[dst[i] >> 6], 1);
    __syncthreads();
    for (int i = threadIdx.x; i < NB; i += 256) {
        int c = cnt[i];
        run[i] = c ? atomicAdd(&gcur[i], c) : 0;
    }
    __syncthreads();
    for (int i = base + threadIdx.x; i < end; i += 256) {
        int d = dst[i];
        int b = d >> 6;
        int pos = atomicAdd(&run[b], 1);
        ebuf[pos] = (unsigned)src[i] | ((unsigned)(d & 63) << 16);
    }
}

// pass B: per-bucket LDS counting sort by dst_low (order-nondeterministic) followed
// by 64 parallel per-dst-segment insertion sorts -> edge lists are the sorted
// (dst,src) multiset: bit-deterministic across replays, at O(n + 64*seg^2/2) cost
// instead of bitonic's O(n log^2 n).
__global__ __launch_bounds__(256) void bucket_sort(const unsigned* __restrict__ ebuf,
                                                   const int* __restrict__ bptr,
                                                   unsigned short* __restrict__ edge_src,
                                                   int* __restrict__ row_ptr) {
    int b = blockIdx.x;
    int start = bptr[b], bend = bptr[b + 1];
    int n = bend - start; if (n > CAP) n = CAP;
    __shared__ unsigned raw[CAP];
    __shared__ unsigned short srt[CAP];
    __shared__ int bins[64], pref[64], cur[64];
    int tid = threadIdx.x;
    for (int i = tid; i < n; i += 256) raw[i] = ebuf[start + i];
    if (tid < 64) bins[tid] = 0;
    __syncthreads();
    for (int i = tid; i < n; i += 256) atomicAdd(&bins[raw[i] >> 16], 1);
    __syncthreads();
    if (tid < 64) {
        int v = bins[tid];
        int incl = v;
        for (int off = 1; off < 64; off <<= 1) {
            int t = __shfl_up(incl, off);
            if (tid >= off) incl += t;
        }
        pref[tid] = incl - v;
        cur[tid] = incl - v;
    }
    __syncthreads();
    // counting scatter into LDS (order within a dst segment is arbitrary here)
    for (int i = tid; i < n; i += 256) {
        unsigned r = raw[i];
        int pos = atomicAdd(&cur[r >> 16], 1);
        srt[pos] = (unsigned short)(r & 0xffffu);
    }
    __syncthreads();
    // canonicalize: insertion-sort each dst segment (avg 16, max ~40 elements)
    if (tid < 64) {
        int s0 = pref[tid];
        int len = bins[tid];
        for (int i = 1; i < len; ++i) {
            unsigned short v = srt[s0 + i];
            int j = i - 1;
            while (j >= 0 && srt[s0 + j] > v) { srt[s0 + j + 1] = srt[s0 + j]; --j; }
            srt[s0 + j + 1] = v;
        }
    }
    __syncthreads();
    for (int i = tid; i < n; i += 256)
        edge_src[start + i] = srt[i];
    int d0 = b * 64;
    if (tid < 64 && d0 + tid < N_NODES) row_ptr[d0 + tid] = start + pref[tid];
}

// ================= weight prep =================

// pre-pack all three W into bf16 fragments Wb[ct][kt][lane][8] (contiguous wb0|wb1|wb2)
__global__ void prep_all(const float* __restrict__ W0, const float* __restrict__ W1,
                         const float* __restrict__ W2, short* __restrict__ Wb) {
    int i = blockIdx.x * 256 + threadIdx.x;
    if (i >= 19 * 2048) return;
    const float* W; int fout; int local;
    if (i < 8 * 2048)       { W = W0; fout = 128; local = i; }
    else if (i < 16 * 2048) { W = W1; fout = 128; local = i - 8 * 2048; }
    else                    { W = W2; fout = 40;  local = i - 16 * 2048; }
    int j = local & 7;
    int l = (local >> 3) & 63;
    int kt = (local >> 9) & 3;
    int ct = local >> 11;
    int col = ct * 16 + (l & 15);
    int k = kt * 32 + (l >> 4) * 8 + j;
    float v = (col < fout) ? W[col * 128 + k] : 0.0f;
    Wb[i] = (short)f2bf(v);
}

// ================= standalone MFMA GEMM (layer 0: x f32 -> h0 bf16) =================

template <int FT>
__global__ __launch_bounds__(256) void gemm_mfma(const float* __restrict__ inp,
                                                 const short* __restrict__ Wb,
                                                 unsigned short* __restrict__ out, int fout) {
    const int l = threadIdx.x & 63;
    const int w = threadIdx.x >> 6;
    const int r16 = l & 15;
    const int khalf = l >> 4;
    int rowA = blockIdx.x * 64 + w * 16 + r16;
    if (rowA >= N_NODES) rowA = N_NODES - 1;  // garbage stays in unstored rows

    f32x4 acc[FT];
#pragma unroll
    for (int ct = 0; ct < FT; ++ct) acc[ct] = (f32x4){0.f, 0.f, 0.f, 0.f};

#pragma unroll
    for (int kt = 0; kt < 4; ++kt) {
        const float* ip = inp + (size_t)rowA * 128 + kt * 32 + khalf * 8;
        float4 f0 = ((const float4*)ip)[0];
        float4 f1 = ((const float4*)ip)[1];
        bf16x8 a;
        a[0] = (short)f2bf(f0.x); a[1] = (short)f2bf(f0.y);
        a[2] = (short)f2bf(f0.z); a[3] = (short)f2bf(f0.w);
        a[4] = (short)f2bf(f1.x); a[5] = (short)f2bf(f1.y);
        a[6] = (short)f2bf(f1.z); a[7] = (short)f2bf(f1.w);
#pragma unroll
        for (int ct = 0; ct < FT; ++ct) {
            bf16x8 bfr = *(const bf16x8*)(Wb + (((ct * 4 + kt) * 64 + l) * 8));
            acc[ct] = __builtin_amdgcn_mfma_f32_16x16x32_bf16(a, bfr, acc[ct], 0, 0, 0);
        }
    }

    const int rowD0 = blockIdx.x * 64 + w * 16 + khalf * 4;
#pragma unroll
    for (int ct = 0; ct < FT; ++ct) {
        int col = ct * 16 + r16;
#pragma unroll
        for (int rr = 0; rr < 4; ++rr) {
            int row = rowD0 + rr;
            if (row < N_NODES && col < fout)
                out[(size_t)row * fout + col] = f2bf(acc[ct][rr]);
        }
    }
}

// ================= fused gather + GEMM (layers 1,2) =================
// Block = 256 threads = 16 nodes. Phase 1: gather bf16 h rows + bias, ReLU,
// into LDS agg[16][132] f32 (pad 132 keeps ds_read_b128 conflicts <=2-way).
// Phase 2: MFMA 16x128 tile; wave w owns col-tiles ct = w, w+4, ...
template <int NCT>
__global__ __launch_bounds__(256) void gather_gemm(const unsigned short* __restrict__ h,
                                                   const int* __restrict__ row_ptr,
                                                   const unsigned short* __restrict__ es,
                                                   const float* __restrict__ bias,
                                                   const short* __restrict__ Wb,
                                                   unsigned short* __restrict__ out, int fout) {
    __shared__ float agg[16][132];
    const int node0 = blockIdx.x * 16;

    {   // ---- gather phase: 16 threads per node, 8 feats each ----
        const int nl = threadIdx.x >> 4;
        const int q  = threadIdx.x & 15;
        const int node = node0 + nl;
        int beg = row_ptr[node], end = row_ptr[node + 1];
        float acc[8];
        float4 c0 = ((const float4*)bias)[q * 2];
        float4 c1 = ((const float4*)bias)[q * 2 + 1];
        acc[0] = c0.x; acc[1] = c0.y; acc[2] = c0.z; acc[3] = c0.w;
        acc[4] = c1.x; acc[5] = c1.y; acc[6] = c1.z; acc[7] = c1.w;
        int e = beg;
        for (; e + 1 < end; e += 2) {
            int s0 = es[e], s1 = es[e + 1];
            const uint4 v0 = ((const uint4*)(h + (size_t)s0 * 128))[q];
            const uint4 v1 = ((const uint4*)(h + (size_t)s1 * 128))[q];
            acc[0] += bfl(v0.x); acc[1] += bfh(v0.x);
            acc[2] += bfl(v0.y); acc[3] += bfh(v0.y);
            acc[4] += bfl(v0.z); acc[5] += bfh(v0.z);
            acc[6] += bfl(v0.w); acc[7] += bfh(v0.w);
            acc[0] += bfl(v1.x); acc[1] += bfh(v1.x);
            acc[2] += bfl(v1.y); acc[3] += bfh(v1.y);
            acc[4] += bfl(v1.z); acc[5] += bfh(v1.z);
            acc[6] += bfl(v1.w); acc[7] += bfh(v1.w);
        }
        if (e < end) {
            int s = es[e];
            const uint4 v = ((const uint4*)(h + (size_t)s * 128))[q];
            acc[0] += bfl(v.x); acc[1] += bfh(v.x);
            acc[2] += bfl(v.y); acc[3] += bfh(v.y);
            acc[4] += bfl(v.z); acc[5] += bfh(v.z);
            acc[6] += bfl(v.w); acc[7] += bfh(v.w);
        }
        float* row = &agg[nl][q * 8];
        ((float4*)row)[0] = make_float4(fmaxf(acc[0], 0.f), fmaxf(acc[1], 0.f),
                                        fmaxf(acc[2], 0.f), fmaxf(acc[3], 0.f));
        ((float4*)row)[1] = make_float4(fmaxf(acc[4], 0.f), fmaxf(acc[5], 0.f),
                                        fmaxf(acc[6], 0.f), fmaxf(acc[7], 0.f));
    }
    __syncthreads();

    // ---- MFMA phase ----
    const int l = threadIdx.x & 63;
    const int w = threadIdx.x >> 6;
    const int r16 = l & 15;
    const int khalf = l >> 4;
    f32x4 acc[(NCT + 3) / 4];
#pragma unroll
    for (int i = 0; i < (NCT + 3) / 4; ++i) acc[i] = (f32x4){0.f, 0.f, 0.f, 0.f};

#pragma unroll
    for (int kt = 0; kt < 4; ++kt) {
        const float* ap = &agg[r16][kt * 32 + khalf * 8];
        float4 f0 = ((const float4*)ap)[0];
        float4 f1 = ((const float4*)ap)[1];
        bf16x8 a;
        a[0] = (short)f2bf(f0.x); a[1] = (short)f2bf(f0.y);
        a[2] = (short)f2bf(f0.z); a[3] = (short)f2bf(f0.w);
        a[4] = (short)f2bf(f1.x); a[5] = (short)f2bf(f1.y);
        a[6] = (short)f2bf(f1.z); a[7] = (short)f2bf(f1.w);
        int i = 0;
#pragma unroll
        for (int ct = w; ct < NCT; ct += 4, ++i) {
            bf16x8 bfr = *(const bf16x8*)(Wb + (((ct * 4 + kt) * 64 + l) * 8));
            acc[i] = __builtin_amdgcn_mfma_f32_16x16x32_bf16(a, bfr, acc[i], 0, 0, 0);
        }
    }

    {
        int i = 0;
#pragma unroll
        for (int ct = w; ct < NCT; ct += 4, ++i) {
            int col = ct * 16 + r16;
            if (col < fout) {
#pragma unroll
                for (int rr = 0; rr < 4; ++rr)
                    out[(size_t)(node0 + khalf * 4 + rr) * fout + col] = f2bf(acc[i][rr]);
            }
        }
    }
}

// ================= final gather (F=40, bf16 in -> f32 out + bias) =================

__global__ void gather_f40_bf(const unsigned short* __restrict__ h,
                              const int* __restrict__ row_ptr,
                              const unsigned short* __restrict__ es,
                              const float* __restrict__ b,
                              float* __restrict__ out) {
    int gid = blockIdx.x * blockDim.x + threadIdx.x;
    int node = gid / 5;
    int q = gid - node * 5;
    if (node >= N_NODES) return;
    int beg = row_ptr[node];
    int end = row_ptr[node + 1];
    float acc[8];
#pragma unroll
    for (int j = 0; j < 8; ++j) acc[j] = b[q * 8 + j];
    int e = beg;
    for (; e + 1 < end; e += 2) {
        int s0 = es[e], s1 = es[e + 1];
        const uint4 v0 = *(const uint4*)(h + (size_t)s0 * 40 + q * 8);
        const uint4 v1 = *(const uint4*)(h + (size_t)s1 * 40 + q * 8);
        acc[0] += bfl(v0.x); acc[1] += bfh(v0.x);
        acc[2] += bfl(v0.y); acc[3] += bfh(v0.y);
        acc[4] += bfl(v0.z); acc[5] += bfh(v0.z);
        acc[6] += bfl(v0.w); acc[7] += bfh(v0.w);
        acc[0] += bfl(v1.x); acc[1] += bfh(v1.x);
        acc[2] += bfl(v1.y); acc[3] += bfh(v1.y);
        acc[4] += bfl(v1.z); acc[5] += bfh(v1.z);
        acc[6] += bfl(v1.w); acc[7] += bfh(v1.w);
    }
    if (e < end) {
        int s = es[e];
        const uint4 v = *(const uint4*)(h + (size_t)s * 40 + q * 8);
        acc[0] += bfl(v.x); acc[1] += bfh(v.x);
        acc[2] += bfl(v.y); acc[3] += bfh(v.y);
        acc[4] += bfl(v.z); acc[5] += bfh(v.z);
        acc[6] += bfl(v.w); acc[7] += bfh(v.w);
    }
    float* o = out + (size_t)node * 40 + q * 8;
    ((float4*)o)[0] = make_float4(acc[0], acc[1], acc[2], acc[3]);
    ((float4*)o)[1] = make_float4(acc[4], acc[5], acc[6], acc[7]);
}

// ================= host =================

extern "C" void kernel_launch(void* const* d_in, const int* in_sizes, int n_in,
                              void* d_out, int out_size, void* d_ws, size_t ws_size,
                              hipStream_t stream) {
    const float* x  = (const float*)d_in[0];
    const int*   ei = (const int*)d_in[1];
    const float* W0 = (const float*)d_in[2];
    const float* b0 = (const float*)d_in[3];
    const float* W1 = (const float*)d_in[4];
    const float* b1 = (const float*)d_in[5];
    const float* W2 = (const float*)d_in[6];
    const float* b2 = (const float*)d_in[7];
    float* out = (float*)d_out;

    const int E = in_sizes[1] / 2;
    const int* src = ei;
    const int* dst = ei + E;

    // workspace layout
    char* p = (char*)d_ws;
    unsigned short* hb0 = (unsigned short*)p;  p += (size_t)N_NODES * 128 * 2;  // L0 out (bf16)
    unsigned short* hb1 = (unsigned short*)p;  p += (size_t)N_NODES * 128 * 2;  // F1 out (bf16)
    unsigned short* hb2 = (unsigned short*)p;  p += (size_t)N_NODES * 40 * 2;   // F2 out (bf16)
    short* wb = (short*)p;                     p += 19 * 2048 * 2;              // wb0|wb1|wb2
    unsigned* ebuf = (unsigned*)p;             p += (size_t)E * 4;
    int* row_ptr = (int*)p;                    p += (N_NODES + 1) * 4;
    int* bptr = (int*)p;                       p += (NB + 1) * 4;
    int* gcnt = (int*)p;                       p += NB * 4;
    int* gcur = (int*)p;                       p += NB * 4;
    unsigned short* edge_src = (unsigned short*)p;  // E u16

    short* wb0 = wb;
    short* wb1 = wb + 8 * 2048;
    short* wb2 = wb + 16 * 2048;

    // ---- CSR build (deterministic: sorted (dst,src) within buckets) ----
    zero_gcnt<<<4, 256, 0, stream>>>(gcnt);
    bucket_hist<<<256, 256, 0, stream>>>(dst, gcnt, E);
    scan_nb<<<1, 1024, 0, stream>>>(gcnt, bptr, gcur, row_ptr, E);
    bucket_scatter<<<(E + PA_CH - 1) / PA_CH, 256, 0, stream>>>(src, dst, gcur, ebuf, E);
    bucket_sort<<<NB, 256, 0, stream>>>(ebuf, bptr, edge_src, row_ptr);

    // ---- weight prep ----
    prep_all<<<(19 * 2048 + 255) / 256, 256, 0, stream>>>(W0, W1, W2, wb);

    // ---- layer 0: h0 = bf16(x @ W0^T) ----
    gemm_mfma<8><<<(N_NODES + 63) / 64, 256, 0, stream>>>(x, wb0, hb0, 128);

    // ---- layer 1 fused: h1 = bf16(relu(gather(h0)+b0) @ W1^T) ----
    gather_gemm<8><<<N_NODES / 16, 256, 0, stream>>>(hb0, row_ptr, edge_src, b0, wb1, hb1, 128);

    // ---- layer 2 fused: h2 = bf16(relu(gather(h1)+b1) @ W2^T) ----
    gather_gemm<3><<<N_NODES / 16, 256, 0, stream>>>(hb1, row_ptr, edge_src, b1, wb2, hb2, 40);

    // ---- final aggregation: out = gather(h2) + b2 ----
    gather_f40_bf<<<(N_NODES * 5 + 255) / 256, 256, 0, stream>>>(hb2, row_ptr, edge_src, b2, out);
}

// Round 10
// 143.024 us; speedup vs baseline: 1.4086x; 1.2389x over previous
//
#include <hip/hip_runtime.h>

#define N_NODES 50000
#define NB 782          // buckets of 64 dst nodes: ceil(50000/64)
#define PA_CH 4096      // edges per block in bucket_scatter
#define CAP 2048        // max edges per bucket (avg 1023; uniform-random tail safe)

typedef __attribute__((ext_vector_type(8))) short bf16x8;
typedef __attribute__((ext_vector_type(4))) float f32x4;

// bf16 helpers (RNE pack, shift unpack)
static __device__ __forceinline__ unsigned short f2bf(float f) {
    unsigned int u = __float_as_uint(f);
    u += 0x7fffu + ((u >> 16) & 1u);
    return (unsigned short)(u >> 16);
}
static __device__ __forceinline__ float bfl(unsigned int u) { return __uint_as_float(u << 16); }
static __device__ __forceinline__ float bfh(unsigned int u) { return __uint_as_float(u & 0xffff0000u); }

// ================= CSR build: 2-level bucket sort (deterministic) =================

__global__ void zero_gcnt(int* __restrict__ g) {
    int i = blockIdx.x * 256 + threadIdx.x;
    if (i < NB) g[i] = 0;
}

__global__ __launch_bounds__(256) void bucket_hist(const int* __restrict__ dst,
                                                   int* __restrict__ gcnt, int E) {
    __shared__ int bins[NB];
    for (int i = threadIdx.x; i < NB; i += 256) bins[i] = 0;
    __syncthreads();
    for (int i = blockIdx.x * 256 + threadIdx.x; i < E; i += gridDim.x * 256)
        atomicAdd(&bins[dst[i] >> 6], 1);
    __syncthreads();
    for (int i = threadIdx.x; i < NB; i += 256) {
        int c = bins[i];
        if (c) atomicAdd(&gcnt[i], c);
    }
}

__global__ __launch_bounds__(1024) void scan_nb(const int* __restrict__ gcnt,
                                                int* __restrict__ bptr, int* __restrict__ gcur,
                                                int* __restrict__ row_ptr, int E) {
    int tid = threadIdx.x;
    int v = (tid < NB) ? gcnt[tid] : 0;
    int lane = tid & 63, wv = tid >> 6;
    int incl = v;
    for (int off = 1; off < 64; off <<= 1) {
        int t = __shfl_up(incl, off);
        if (lane >= off) incl += t;
    }
    __shared__ int ws[16];
    if (lane == 63) ws[wv] = incl;
    __syncthreads();
    int woff = 0;
    for (int i = 0; i < wv; ++i) woff += ws[i];
    int excl = woff + incl - v;
    if (tid < NB) { bptr[tid] = excl; gcur[tid] = excl; }
    if (tid == NB - 1) { bptr[NB] = excl + v; row_ptr[N_NODES] = E; }
}

// pass A: scatter packed (src | dst_low6<<16) into bucket regions (order nondeterministic,
// harmless: pass B canonicalizes each bucket)
__global__ __launch_bounds__(256) void bucket_scatter(const int* __restrict__ src,
                                                      const int* __restrict__ dst,
                                                      int* __restrict__ gcur,
                                                      unsigned* __restrict__ ebuf, int E) {
    __shared__ int cnt[NB];
    __shared__ int run[NB];
    int base = blockIdx.x * PA_CH;
    int end = base + PA_CH; if (end > E) end = E;
    for (int i = threadIdx.x; i < NB; i += 256) cnt[i] = 0;
    __syncthreads();
    for (int i = base + threadIdx.x; i < end; i += 256)
        atomicAdd(&cnt[dst[i] >> 6], 1);
    __syncthreads();
    for (int i = threadIdx.x; i < NB; i += 256) {
        int c = cnt[i];
        run[i] = c ? atomicAdd(&gcur[i], c) : 0;
    }
    __syncthreads();
    for (int i = base + threadIdx.x; i < end; i += 256) {
        int d = dst[i];
        int b = d >> 6;
        int pos = atomicAdd(&run[b], 1);
        ebuf[pos] = (unsigned)src[i] | ((unsigned)(d & 63) << 16);
    }
}

// pass B: per-bucket LDS counting scatter by dst_low (arrival-ordered), then a
// PARALLEL RANK-SORT within each dst segment: each element computes
// rank = #(v_j < v_i) + #(v_j == v_i && j < i) over its segment and writes to
// seg_lo + rank. Duplicate (dst,src) edges are identical u16 values, so the
// output array is a deterministic function of the edge multiset even though the
// tie-break position is arrival-ordered. Loop is independent LDS reads
// (pipelines; no serial dependency like insertion sort).
__global__ __launch_bounds__(256) void bucket_sort(const unsigned* __restrict__ ebuf,
                                                   const int* __restrict__ bptr,
                                                   unsigned short* __restrict__ edge_src,
                                                   int* __restrict__ row_ptr) {
    int b = blockIdx.x;
    int start = bptr[b], bend = bptr[b + 1];
    int n = bend - start; if (n > CAP) n = CAP;
    __shared__ unsigned raw[CAP];
    __shared__ unsigned grp[CAP];     // segment-grouped full keys (seg<<16 | src)
    __shared__ int bins[64], pref[64], cur[64];
    int tid = threadIdx.x;
    for (int i = tid; i < n; i += 256) raw[i] = ebuf[start + i];
    if (tid < 64) bins[tid] = 0;
    __syncthreads();
    for (int i = tid; i < n; i += 256) atomicAdd(&bins[raw[i] >> 16], 1);
    __syncthreads();
    if (tid < 64) {
        int v = bins[tid];
        int incl = v;
        for (int off = 1; off < 64; off <<= 1) {
            int t = __shfl_up(incl, off);
            if (tid >= off) incl += t;
        }
        pref[tid] = incl - v;
        cur[tid] = incl - v;
    }
    __syncthreads();
    // counting scatter into grouped LDS (order within a segment is arbitrary)
    for (int i = tid; i < n; i += 256) {
        unsigned r = raw[i];
        int pos = atomicAdd(&cur[r >> 16], 1);
        grp[pos] = r;
    }
    __syncthreads();
    // parallel rank-sort: independent loads, no serial chain
    for (int i = tid; i < n; i += 256) {
        unsigned v = grp[i];
        int s = v >> 16;
        int lo = pref[s];
        int len = bins[s];
        int rank = 0;
        for (int j = lo; j < lo + len; ++j) {
            unsigned u = grp[j];
            rank += (u < v) || (u == v && j < i);
        }
        edge_src[start + lo + rank] = (unsigned short)(v & 0xffffu);
    }
    int d0 = b * 64;
    if (tid < 64 && d0 + tid < N_NODES) row_ptr[d0 + tid] = start + pref[tid];
}

// ================= weight prep =================

// pre-pack all three W into bf16 fragments Wb[ct][kt][lane][8] (contiguous wb0|wb1|wb2)
__global__ void prep_all(const float* __restrict__ W0, const float* __restrict__ W1,
                         const float* __restrict__ W2, short* __restrict__ Wb) {
    int i = blockIdx.x * 256 + threadIdx.x;
    if (i >= 19 * 2048) return;
    const float* W; int fout; int local;
    if (i < 8 * 2048)       { W = W0; fout = 128; local = i; }
    else if (i < 16 * 2048) { W = W1; fout = 128; local = i - 8 * 2048; }
    else                    { W = W2; fout = 40;  local = i - 16 * 2048; }
    int j = local & 7;
    int l = (local >> 3) & 63;
    int kt = (local >> 9) & 3;
    int ct = local >> 11;
    int col = ct * 16 + (l & 15);
    int k = kt * 32 + (l >> 4) * 8 + j;
    float v = (col < fout) ? W[col * 128 + k] : 0.0f;
    Wb[i] = (short)f2bf(v);
}

// ================= standalone MFMA GEMM (layer 0: x f32 -> h0 bf16) =================

template <int FT>
__global__ __launch_bounds__(256) void gemm_mfma(const float* __restrict__ inp,
                                                 const short* __restrict__ Wb,
                                                 unsigned short* __restrict__ out, int fout) {
    const int l = threadIdx.x & 63;
    const int w = threadIdx.x >> 6;
    const int r16 = l & 15;
    const int khalf = l >> 4;
    int rowA = blockIdx.x * 64 + w * 16 + r16;
    if (rowA >= N_NODES) rowA = N_NODES - 1;  // garbage stays in unstored rows

    f32x4 acc[FT];
#pragma unroll
    for (int ct = 0; ct < FT; ++ct) acc[ct] = (f32x4){0.f, 0.f, 0.f, 0.f};

#pragma unroll
    for (int kt = 0; kt < 4; ++kt) {
        const float* ip = inp + (size_t)rowA * 128 + kt * 32 + khalf * 8;
        float4 f0 = ((const float4*)ip)[0];
        float4 f1 = ((const float4*)ip)[1];
        bf16x8 a;
        a[0] = (short)f2bf(f0.x); a[1] = (short)f2bf(f0.y);
        a[2] = (short)f2bf(f0.z); a[3] = (short)f2bf(f0.w);
        a[4] = (short)f2bf(f1.x); a[5] = (short)f2bf(f1.y);
        a[6] = (short)f2bf(f1.z); a[7] = (short)f2bf(f1.w);
#pragma unroll
        for (int ct = 0; ct < FT; ++ct) {
            bf16x8 bfr = *(const bf16x8*)(Wb + (((ct * 4 + kt) * 64 + l) * 8));
            acc[ct] = __builtin_amdgcn_mfma_f32_16x16x32_bf16(a, bfr, acc[ct], 0, 0, 0);
        }
    }

    const int rowD0 = blockIdx.x * 64 + w * 16 + khalf * 4;
#pragma unroll
    for (int ct = 0; ct < FT; ++ct) {
        int col = ct * 16 + r16;
#pragma unroll
        for (int rr = 0; rr < 4; ++rr) {
            int row = rowD0 + rr;
            if (row < N_NODES && col < fout)
                out[(size_t)row * fout + col] = f2bf(acc[ct][rr]);
        }
    }
}

// ================= fused gather + GEMM (layers 1,2) =================
// Block = 256 threads = 16 nodes. Phase 1: gather bf16 h rows + bias, ReLU,
// into LDS agg[16][132] f32 (pad 132 keeps ds_read_b128 conflicts <=2-way).
// Phase 2: MFMA 16x128 tile; wave w owns col-tiles ct = w, w+4, ...
template <int NCT>
__global__ __launch_bounds__(256) void gather_gemm(const unsigned short* __restrict__ h,
                                                   const int* __restrict__ row_ptr,
                                                   const unsigned short* __restrict__ es,
                                                   const float* __restrict__ bias,
                                                   const short* __restrict__ Wb,
                                                   unsigned short* __restrict__ out, int fout) {
    __shared__ float agg[16][132];
    const int node0 = blockIdx.x * 16;

    {   // ---- gather phase: 16 threads per node, 8 feats each ----
        const int nl = threadIdx.x >> 4;
        const int q  = threadIdx.x & 15;
        const int node = node0 + nl;
        int beg = row_ptr[node], end = row_ptr[node + 1];
        float acc[8];
        float4 c0 = ((const float4*)bias)[q * 2];
        float4 c1 = ((const float4*)bias)[q * 2 + 1];
        acc[0] = c0.x; acc[1] = c0.y; acc[2] = c0.z; acc[3] = c0.w;
        acc[4] = c1.x; acc[5] = c1.y; acc[6] = c1.z; acc[7] = c1.w;
        int e = beg;
        for (; e + 1 < end; e += 2) {
            int s0 = es[e], s1 = es[e + 1];
            const uint4 v0 = ((const uint4*)(h + (size_t)s0 * 128))[q];
            const uint4 v1 = ((const uint4*)(h + (size_t)s1 * 128))[q];
            acc[0] += bfl(v0.x); acc[1] += bfh(v0.x);
            acc[2] += bfl(v0.y); acc[3] += bfh(v0.y);
            acc[4] += bfl(v0.z); acc[5] += bfh(v0.z);
            acc[6] += bfl(v0.w); acc[7] += bfh(v0.w);
            acc[0] += bfl(v1.x); acc[1] += bfh(v1.x);
            acc[2] += bfl(v1.y); acc[3] += bfh(v1.y);
            acc[4] += bfl(v1.z); acc[5] += bfh(v1.z);
            acc[6] += bfl(v1.w); acc[7] += bfh(v1.w);
        }
        if (e < end) {
            int s = es[e];
            const uint4 v = ((const uint4*)(h + (size_t)s * 128))[q];
            acc[0] += bfl(v.x); acc[1] += bfh(v.x);
            acc[2] += bfl(v.y); acc[3] += bfh(v.y);
            acc[4] += bfl(v.z); acc[5] += bfh(v.z);
            acc[6] += bfl(v.w); acc[7] += bfh(v.w);
        }
        float* row = &agg[nl][q * 8];
        ((float4*)row)[0] = make_float4(fmaxf(acc[0], 0.f), fmaxf(acc[1], 0.f),
                                        fmaxf(acc[2], 0.f), fmaxf(acc[3], 0.f));
        ((float4*)row)[1] = make_float4(fmaxf(acc[4], 0.f), fmaxf(acc[5], 0.f),
                                        fmaxf(acc[6], 0.f), fmaxf(acc[7], 0.f));
    }
    __syncthreads();

    // ---- MFMA phase ----
    const int l = threadIdx.x & 63;
    const int w = threadIdx.x >> 6;
    const int r16 = l & 15;
    const int khalf = l >> 4;
    f32x4 acc[(NCT + 3) / 4];
#pragma unroll
    for (int i = 0; i < (NCT + 3) / 4; ++i) acc[i] = (f32x4){0.f, 0.f, 0.f, 0.f};

#pragma unroll
    for (int kt = 0; kt < 4; ++kt) {
        const float* ap = &agg[r16][kt * 32 + khalf * 8];
        float4 f0 = ((const float4*)ap)[0];
        float4 f1 = ((const float4*)ap)[1];
        bf16x8 a;
        a[0] = (short)f2bf(f0.x); a[1] = (short)f2bf(f0.y);
        a[2] = (short)f2bf(f0.z); a[3] = (short)f2bf(f0.w);
        a[4] = (short)f2bf(f1.x); a[5] = (short)f2bf(f1.y);
        a[6] = (short)f2bf(f1.z); a[7] = (short)f2bf(f1.w);
        int i = 0;
#pragma unroll
        for (int ct = w; ct < NCT; ct += 4, ++i) {
            bf16x8 bfr = *(const bf16x8*)(Wb + (((ct * 4 + kt) * 64 + l) * 8));
            acc[i] = __builtin_amdgcn_mfma_f32_16x16x32_bf16(a, bfr, acc[i], 0, 0, 0);
        }
    }

    {
        int i = 0;
#pragma unroll
        for (int ct = w; ct < NCT; ct += 4, ++i) {
            int col = ct * 16 + r16;
            if (col < fout) {
#pragma unroll
                for (int rr = 0; rr < 4; ++rr)
                    out[(size_t)(node0 + khalf * 4 + rr) * fout + col] = f2bf(acc[i][rr]);
            }
        }
    }
}

// ================= final gather (F=40, bf16 in -> f32 out + bias) =================

__global__ void gather_f40_bf(const unsigned short* __restrict__ h,
                              const int* __restrict__ row_ptr,
                              const unsigned short* __restrict__ es,
                              const float* __restrict__ b,
                              float* __restrict__ out) {
    int gid = blockIdx.x * blockDim.x + threadIdx.x;
    int node = gid / 5;
    int q = gid - node * 5;
    if (node >= N_NODES) return;
    int beg = row_ptr[node];
    int end = row_ptr[node + 1];
    float acc[8];
#pragma unroll
    for (int j = 0; j < 8; ++j) acc[j] = b[q * 8 + j];
    int e = beg;
    for (; e + 1 < end; e += 2) {
        int s0 = es[e], s1 = es[e + 1];
        const uint4 v0 = *(const uint4*)(h + (size_t)s0 * 40 + q * 8);
        const uint4 v1 = *(const uint4*)(h + (size_t)s1 * 40 + q * 8);
        acc[0] += bfl(v0.x); acc[1] += bfh(v0.x);
        acc[2] += bfl(v0.y); acc[3] += bfh(v0.y);
        acc[4] += bfl(v0.z); acc[5] += bfh(v0.z);
        acc[6] += bfl(v0.w); acc[7] += bfh(v0.w);
        acc[0] += bfl(v1.x); acc[1] += bfh(v1.x);
        acc[2] += bfl(v1.y); acc[3] += bfh(v1.y);
        acc[4] += bfl(v1.z); acc[5] += bfh(v1.z);
        acc[6] += bfl(v1.w); acc[7] += bfh(v1.w);
    }
    if (e < end) {
        int s = es[e];
        const uint4 v = *(const uint4*)(h + (size_t)s * 40 + q * 8);
        acc[0] += bfl(v.x); acc[1] += bfh(v.x);
        acc[2] += bfl(v.y); acc[3] += bfh(v.y);
        acc[4] += bfl(v.z); acc[5] += bfh(v.z);
        acc[6] += bfl(v.w); acc[7] += bfh(v.w);
    }
    float* o = out + (size_t)node * 40 + q * 8;
    ((float4*)o)[0] = make_float4(acc[0], acc[1], acc[2], acc[3]);
    ((float4*)o)[1] = make_float4(acc[4], acc[5], acc[6], acc[7]);
}

// ================= host =================

extern "C" void kernel_launch(void* const* d_in, const int* in_sizes, int n_in,
                              void* d_out, int out_size, void* d_ws, size_t ws_size,
                              hipStream_t stream) {
    const float* x  = (const float*)d_in[0];
    const int*   ei = (const int*)d_in[1];
    const float* W0 = (const float*)d_in[2];
    const float* b0 = (const float*)d_in[3];
    const float* W1 = (const float*)d_in[4];
    const float* b1 = (const float*)d_in[5];
    const float* W2 = (const float*)d_in[6];
    const float* b2 = (const float*)d_in[7];
    float* out = (float*)d_out;

    const int E = in_sizes[1] / 2;
    const int* src = ei;
    const int* dst = ei + E;

    // workspace layout
    char* p = (char*)d_ws;
    unsigned short* hb0 = (unsigned short*)p;  p += (size_t)N_NODES * 128 * 2;  // L0 out (bf16)
    unsigned short* hb1 = (unsigned short*)p;  p += (size_t)N_NODES * 128 * 2;  // F1 out (bf16)
    unsigned short* hb2 = (unsigned short*)p;  p += (size_t)N_NODES * 40 * 2;   // F2 out (bf16)
    short* wb = (short*)p;                     p += 19 * 2048 * 2;              // wb0|wb1|wb2
    unsigned* ebuf = (unsigned*)p;             p += (size_t)E * 4;
    int* row_ptr = (int*)p;                    p += (N_NODES + 1) * 4;
    int* bptr = (int*)p;                       p += (NB + 1) * 4;
    int* gcnt = (int*)p;                       p += NB * 4;
    int* gcur = (int*)p;                       p += NB * 4;
    unsigned short* edge_src = (unsigned short*)p;  // E u16

    short* wb0 = wb;
    short* wb1 = wb + 8 * 2048;
    short* wb2 = wb + 16 * 2048;

    // ---- CSR build (deterministic: sorted (dst,src) within buckets) ----
    zero_gcnt<<<4, 256, 0, stream>>>(gcnt);
    bucket_hist<<<256, 256, 0, stream>>>(dst, gcnt, E);
    scan_nb<<<1, 1024, 0, stream>>>(gcnt, bptr, gcur, row_ptr, E);
    bucket_scatter<<<(E + PA_CH - 1) / PA_CH, 256, 0, stream>>>(src, dst, gcur, ebuf, E);
    bucket_sort<<<NB, 256, 0, stream>>>(ebuf, bptr, edge_src, row_ptr);

    // ---- weight prep ----
    prep_all<<<(19 * 2048 + 255) / 256, 256, 0, stream>>>(W0, W1, W2, wb);

    // ---- layer 0: h0 = bf16(x @ W0^T) ----
    gemm_mfma<8><<<(N_NODES + 63) / 64, 256, 0, stream>>>(x, wb0, hb0, 128);

    // ---- layer 1 fused: h1 = bf16(relu(gather(h0)+b0) @ W1^T) ----
    gather_gemm<8><<<N_NODES / 16, 256, 0, stream>>>(hb0, row_ptr, edge_src, b0, wb1, hb1, 128);

    // ---- layer 2 fused: h2 = bf16(relu(gather(h1)+b1) @ W2^T) ----
    gather_gemm<3><<<N_NODES / 16, 256, 0, stream>>>(hb1, row_ptr, edge_src, b1, wb2, hb2, 40);

    // ---- final aggregation: out = gather(h2) + b2 ----
    gather_f40_bf<<<(N_NODES * 5 + 255) / 256, 256, 0, stream>>>(hb2, row_ptr, edge_src, b2, out);
}